// Round 6
// baseline (448.043 us; speedup 1.0000x reference)
//
#include <hip/hip_runtime.h>

using u16 = unsigned short;
using u32 = unsigned int;

typedef __attribute__((ext_vector_type(8))) __bf16 bf16x8;
typedef __attribute__((ext_vector_type(4))) float f32x4;
typedef __attribute__((ext_vector_type(4))) u32 u32x4;

#define GLOAD16(gp, lp) __builtin_amdgcn_global_load_lds( \
    (const __attribute__((address_space(1))) void*)(gp),  \
    (__attribute__((address_space(3))) void*)(lp), 16, 0, 0)

__device__ __forceinline__ u16 f2b(float f) {
  u32 u = __builtin_bit_cast(u32, f);
  u += 0x7fffu + ((u >> 16) & 1u);
  return (u16)(u >> 16);
}
__device__ __forceinline__ float b2f(u16 h) {
  return __builtin_bit_cast(float, (u32)h << 16);
}
__device__ __forceinline__ u32 cvtpk(float lo, float hi) {
  u32 r;
  asm("v_cvt_pk_bf16_f32 %0, %1, %2" : "=v"(r) : "v"(lo), "v"(hi));
  return r;
}

// ---------------- cast hs -> bf16 ----------------
__global__ __launch_bounds__(256) void cast_k(
    const float* __restrict__ in, u16* __restrict__ o1, int n) {
  int i = (blockIdx.x * 256 + threadIdx.x) * 4;
  if (i >= n) return;
  float4 v = *(const float4*)&in[i];
  *(uint2*)&o1[i] = make_uint2((u32)f2b(v.x) | ((u32)f2b(v.y) << 16),
                               (u32)f2b(v.z) | ((u32)f2b(v.w) << 16));
}

// ---------------- transpose + cast weight: out[e][d] = in[d][e] ----------------
__global__ __launch_bounds__(256) void transpose_cast_k(
    const float* __restrict__ in, u16* __restrict__ out, int D) {
  __shared__ float t[32][33];
  const int tx = threadIdx.x & 31, ty = threadIdx.x >> 5;
  const int e0 = blockIdx.x * 32, d0 = blockIdx.y * 32;
  #pragma unroll
  for (int i = ty; i < 32; i += 8) t[i][tx] = in[(size_t)(d0 + i) * D + e0 + tx];
  __syncthreads();
  #pragma unroll
  for (int i = ty; i < 32; i += 8) out[(size_t)(e0 + i) * D + d0 + tx] = f2b(t[tx][i]);
}

// ------ combined compression weight: outT[h*32+c][d] = sum_dp Wfull[d][h*128+dp]*Wc[dp][c] ------
__global__ __launch_bounds__(256) void combine_k(
    const float* __restrict__ Wfull, const float* __restrict__ Wc,
    u16* __restrict__ outT, int D) {
  __shared__ float wl[4096];
  const int tid = threadIdx.x;
  for (int i = tid; i < 4096; i += 256) wl[i] = Wc[i];
  __syncthreads();
  const int h = blockIdx.y;
  const int d = blockIdx.x * 256 + tid;
  const float* wkr = Wfull + (size_t)d * D + h * 128;
  float acc[32] = {};
  for (int dp = 0; dp < 128; ++dp) {
    const float wv = wkr[dp];
    const float* w2 = &wl[dp * 32];
    #pragma unroll
    for (int c = 0; c < 32; ++c) acc[c] += wv * w2[c];
  }
  #pragma unroll
  for (int c = 0; c < 32; ++c)
    outT[(size_t)(h * 32 + c) * D + d] = f2b(acc[c]);
}

// ---------------- expansion weight transpose: out[d][c] = bf16(in[c][d]), 32x128 ----------------
__global__ __launch_bounds__(256) void wtrans_k(
    const float* __restrict__ in, u16* __restrict__ out) {
  const int i = blockIdx.x * 256 + threadIdx.x;  // 4096 total
  const int d = i >> 5, c = i & 31;
  out[i] = f2b(in[c * 128 + d]);
}

// ---------------- expansion via MFMA ----------------
// in: [bh][2048][32] bf16, WT: [128][32] bf16 (Wexp^T)
// TRANS=0 (K): out[bh][s][128]   TRANS=1 (V): out[bh][128][2048] (d-major)
template <int TRANS>
__global__ __launch_bounds__(256) void expand_mfma_k(
    const u16* __restrict__ in, const u16* __restrict__ WT, u16* __restrict__ out) {
  __shared__ alignas(16) u16 WL[128 * 32];
  __shared__ alignas(16) u16 ct[64 * 40];
  const int tid = threadIdx.x, lane = tid & 63, w = tid >> 6;
  const int cl = lane & 15, g = lane >> 4;
  const int bh = blockIdx.y, s0 = blockIdx.x * 64;
  for (int i = tid; i < 512; i += 256) ((uint4*)WL)[i] = ((const uint4*)WT)[i];
  {
    const int r = tid >> 2, co = (tid & 3) * 8;
    *(uint4*)&ct[r * 40 + co] =
        *(const uint4*)&in[((size_t)bh * 2048 + s0 + r) * 32 + co];
  }
  __syncthreads();
  f32x4 acc[2][4] = {};
  #pragma unroll
  for (int dti = 0; dti < 2; ++dti) {
    const bf16x8 wf = *(const bf16x8*)&WL[((w * 2 + dti) * 16 + cl) * 32 + g * 8];
    #pragma unroll
    for (int st = 0; st < 4; ++st) {
      const bf16x8 cf = *(const bf16x8*)&ct[(st * 16 + cl) * 40 + g * 8];
      if constexpr (TRANS)
        acc[dti][st] = __builtin_amdgcn_mfma_f32_16x16x32_bf16(wf, cf, acc[dti][st], 0, 0, 0);
      else
        acc[dti][st] = __builtin_amdgcn_mfma_f32_16x16x32_bf16(cf, wf, acc[dti][st], 0, 0, 0);
    }
  }
  #pragma unroll
  for (int dti = 0; dti < 2; ++dti) {
    #pragma unroll
    for (int st = 0; st < 4; ++st) {
      #pragma unroll
      for (int r = 0; r < 4; ++r) {
        if constexpr (TRANS) {
          const int d = (w * 2 + dti) * 16 + g * 4 + r;
          const int s = s0 + st * 16 + cl;
          out[((size_t)bh * 128 + d) * 2048 + s] = f2b(acc[dti][st][r]);
        } else {
          const int s = s0 + st * 16 + g * 4 + r;
          const int d = (w * 2 + dti) * 16 + cl;
          out[((size_t)bh * 2048 + s) * 128 + d] = f2b(acc[dti][st][r]);
        }
      }
    }
  }
}

// ---------------- ring-4 counted-vmcnt GEMM ----------------
// C[M, BN*16] = A[M,2048] * Bt[N,2048]^T, BM=256, BK=32, 8 waves (2M x 4N).
// Ring of 4 LDS tile-buffers; stage tile t+3 during compute(t); vmcnt counted
// (never 0 in steady state); ONE raw s_barrier per tile.
// MODE 0 (BN=192): fused QKV epilogue. MODE 1 (BN=128): f32 [M,2048] out.
template <int BN, int MODE>
__global__ __launch_bounds__(512, 1) void gemm_ring_k(
    const u16* __restrict__ A, const u16* __restrict__ Bt,
    u16* __restrict__ qb, float* __restrict__ out_kc, u16* __restrict__ kcb,
    float* __restrict__ out_vc, u16* __restrict__ vcb,
    float* __restrict__ outF) {
  constexpr int NR = BN / 64;          // per-wave N fragments
  __shared__ alignas(16) u16 As[4][256 * 32];
  __shared__ alignas(16) u16 Bs[4][BN * 32];
  const int tid = threadIdx.x, lane = tid & 63, w = tid >> 6;
  const int l15 = lane & 15, lhi = lane >> 4;
  const int m0 = blockIdx.y * 256, n0 = blockIdx.x * BN;
  const int wr = (w >> 2) * 128, wc = (w & 3) * (BN / 4);

  f32x4 acc[8][NR] = {};

#define GSTAGE(T, BUF)                                                        \
  {                                                                           \
    const int kk0 = (T) * 32;                                                 \
    const int idx0 = tid;                                                     \
    GLOAD16(A + (size_t)(m0 + (idx0 >> 2)) * 2048 + kk0 + (idx0 & 3) * 8,     \
            &As[BUF][idx0 * 8]);                                              \
    const int idx1 = 512 + tid;                                               \
    GLOAD16(A + (size_t)(m0 + (idx1 >> 2)) * 2048 + kk0 + (idx1 & 3) * 8,     \
            &As[BUF][idx1 * 8]);                                              \
    const int jdx0 = tid;                                                     \
    GLOAD16(Bt + (size_t)(n0 + (jdx0 >> 2)) * 2048 + kk0 + (jdx0 & 3) * 8,    \
            &Bs[BUF][jdx0 * 8]);                                              \
    if constexpr (BN == 192) {                                                \
      const int jdx1 = 512 + (tid & 255); /* dup write, same data: benign */  \
      GLOAD16(Bt + (size_t)(n0 + (jdx1 >> 2)) * 2048 + kk0 + (jdx1 & 3) * 8,  \
              &Bs[BUF][jdx1 * 8]);                                            \
    }                                                                         \
  }

  GSTAGE(0, 0);
  GSTAGE(1, 1);
  GSTAGE(2, 2);

  for (int t = 0; t < 64; ++t) {
    const int buf = t & 3;
    if (t < 62) {
      if constexpr (BN == 192) asm volatile("s_waitcnt vmcnt(8)" ::: "memory");
      else                     asm volatile("s_waitcnt vmcnt(6)" ::: "memory");
    } else if (t == 62) {
      if constexpr (BN == 192) asm volatile("s_waitcnt vmcnt(4)" ::: "memory");
      else                     asm volatile("s_waitcnt vmcnt(3)" ::: "memory");
    } else {
      asm volatile("s_waitcnt vmcnt(0)" ::: "memory");
    }
    __builtin_amdgcn_s_barrier();
    asm volatile("" ::: "memory");

    bf16x8 bfrag[NR];
    #pragma unroll
    for (int n = 0; n < NR; ++n)
      bfrag[n] = *(const bf16x8*)&Bs[buf][(wc + n * 16 + l15) * 32 + lhi * 8];
    __builtin_amdgcn_s_setprio(1);
    #pragma unroll
    for (int m = 0; m < 8; ++m) {
      const bf16x8 af = *(const bf16x8*)&As[buf][(wr + m * 16 + l15) * 32 + lhi * 8];
      #pragma unroll
      for (int n = 0; n < NR; ++n)
        acc[m][n] = __builtin_amdgcn_mfma_f32_16x16x32_bf16(af, bfrag[n], acc[m][n], 0, 0, 0);
    }
    __builtin_amdgcn_s_setprio(0);
    asm volatile("" ::: "memory");

    if (t + 3 < 64) GSTAGE(t + 3, (t + 3) & 3);
  }
#undef GSTAGE

  const float qscale = 0.08838834764831845f * 1.4426950408889634f;
  #pragma unroll
  for (int m = 0; m < 8; ++m) {
    #pragma unroll
    for (int n = 0; n < NR; ++n) {
      #pragma unroll
      for (int r = 0; r < 4; ++r) {
        const int row = m0 + wr + m * 16 + lhi * 4 + r;
        const int col = n0 + wc + n * 16 + l15;
        const float v = acc[m][n][r];
        if constexpr (MODE == 0) {
          const int b = row >> 11, s = row & 2047;
          if (col < 2048) {
            const int h = col >> 7, dh = col & 127;
            qb[((size_t)(b * 16 + h) * 2048 + s) * 128 + dh] = f2b(v * qscale);
          } else {
            const int cc = col - 2048;
            if (cc < 512) {
              const int h = cc >> 5, c = cc & 31;
              const size_t idx = ((size_t)(b * 16 + h) * 2048 + s) * 32 + c;
              out_kc[idx] = v;
              kcb[idx] = f2b(v);
            } else {
              const int cc2 = cc - 512;
              const int h = cc2 >> 5, c = cc2 & 31;
              const size_t idx = ((size_t)(b * 16 + h) * 2048 + s) * 32 + c;
              out_vc[idx] = v;
              vcb[idx] = f2b(v);
            }
          }
        } else {
          outF[(size_t)row * 2048 + col] = v;
        }
      }
    }
  }
}

// ---------------- causal flash attention v4 (occupancy-fixed) ----------------
// 8 waves: waves 0-3 own q-tile A=i, waves 4-7 own q-tile B=31-i, processing the
// SAME staged K/V tile concurrently. grid (16, B*H).
// q: [bh][s][128] bf16 PRE-SCALED (incl log2e); kh: [bh][s][128]; vt: [bh][128][s]
__global__ __launch_bounds__(512, 2) void attn_k(
    const u16* __restrict__ q, const u16* __restrict__ kh,
    const u16* __restrict__ vt, u16* __restrict__ ctx) {
  __shared__ alignas(16) u16 Ks[2][64 * 128];   // [k][d], XOR-swizzled 16B chunks
  __shared__ alignas(16) u16 Vs[2][128 * 64];   // [d][k], XOR-swizzled 16B chunks
  const int tid = threadIdx.x, lane = tid & 63, w = tid >> 6;
  const int grp = w >> 2, wq = w & 3;
  const int c = lane & 15, g = lane >> 4;
  const int iA = blockIdx.x, iB = 31 - iA, bh = blockIdx.y;
  const int qt = grp ? iB : iA;
  const size_t base = (size_t)bh * (2048 * 128);

  // Q fragments (B-operand layout): lane holds Q[q=c][d = ks*32+g*8 ..+7]
  bf16x8 qf[4];
  {
    const int qrow = qt * 64 + wq * 16 + c;
    #pragma unroll
    for (int ks = 0; ks < 4; ++ks)
      qf[ks] = *(const bf16x8*)&q[base + (size_t)qrow * 128 + ks * 32 + g * 8];
  }

  f32x4 of[8] = {};
  float m = -__builtin_inff(), l = 0.f;
  const int srcLo = lane ^ (((4 - g) & 3) << 4);
  const int srcHi = lane ^ (((g + 1) & 3) << 4);
  const int alS = (lane & 48) + ((lane & 48) >> 2);
  const bool hiSel = (g >> 1) != 0;

#define STAGE(J, BUF)                                                          \
  {                                                                            \
    _Pragma("unroll")                                                          \
    for (int i2 = 0; i2 < 2; ++i2) {                                           \
      const int rowgrp = w * 8 + i2 * 4;                                       \
      const int rloc = rowgrp + (lane >> 4);                                   \
      const int srce = ((c * 16) ^ ((rloc & 7) << 4)) >> 1;                    \
      GLOAD16(kh + base + (size_t)((J) * 64 + rloc) * 128 + srce,              \
              &Ks[BUF][rowgrp * 128]);                                         \
    }                                                                          \
    _Pragma("unroll")                                                          \
    for (int i2 = 0; i2 < 2; ++i2) {                                           \
      const int d0 = (w * 2 + i2) * 8;                                         \
      const int dd = d0 + (lane >> 3);                                         \
      const int cc = lane & 7;                                                 \
      GLOAD16(vt + base + (size_t)dd * 2048 + (J) * 64 + ((cc ^ (dd & 7)) * 8),\
              &Vs[BUF][d0 * 64]);                                              \
    }                                                                          \
  }

  STAGE(0, 0);
  for (int j = 0; j <= iB; ++j) {
    const int buf = j & 1;
    __syncthreads();                       // stage(j) complete (vmcnt drained)
    if (j < iB) STAGE(j + 1, buf ^ 1);     // prefetch next tile under compute
    if (j <= qt) {
      // S^T = K Q^T : sf[n][r] = S[q=c][k = n*16 + g*4 + r]
      f32x4 sf[4] = {};
      const char* ksb0 = (const char*)&Ks[buf][0];
      __builtin_amdgcn_s_setprio(1);
      #pragma unroll
      for (int n = 0; n < 4; ++n) {
        const int row = n * 16 + c;
        const char* kb = ksb0 + row * 256;
        #pragma unroll
        for (int ks = 0; ks < 4; ++ks) {
          const bf16x8 kf =
              *(const bf16x8*)(kb + ((ks * 64 + g * 16) ^ ((row & 7) << 4)));
          sf[n] = __builtin_amdgcn_mfma_f32_16x16x32_bf16(kf, qf[ks], sf[n], 0, 0, 0);
        }
      }
      __builtin_amdgcn_s_setprio(0);
      if (j == qt) {  // diagonal causal mask
        const int qloc = wq * 16 + c;
        #pragma unroll
        for (int n = 0; n < 4; ++n)
          #pragma unroll
          for (int r = 0; r < 4; ++r)
            if (n * 16 + g * 4 + r > qloc) sf[n][r] = -__builtin_inff();
      }
      // row max for q=c (in-lane 16 + cross-g)
      float smax = sf[0][0];
      #pragma unroll
      for (int n = 0; n < 4; ++n)
        #pragma unroll
        for (int r = 0; r < 4; ++r) smax = fmaxf(smax, sf[n][r]);
      smax = fmaxf(smax, __shfl_xor(smax, 16, 64));
      smax = fmaxf(smax, __shfl_xor(smax, 32, 64));
      if (__any(smax - m > 12.0f)) {  // defer-max (T13)
        const float mn = fmaxf(m, smax);
        const float al = exp2f(m - mn);
        m = mn;
        l *= al;
        float alr[4];
        #pragma unroll
        for (int r = 0; r < 4; ++r) alr[r] = __shfl(al, alS + r, 64);
        #pragma unroll
        for (int nd = 0; nd < 8; ++nd)
          #pragma unroll
          for (int r = 0; r < 4; ++r) of[nd][r] *= alr[r];
      }
      float rs = 0.f;
      #pragma unroll
      for (int n = 0; n < 4; ++n)
        #pragma unroll
        for (int r = 0; r < 4; ++r) {
          const float p = exp2f(sf[n][r] - m);
          sf[n][r] = p;
          rs += p;
        }
      rs += __shfl_xor(rs, 16, 64);
      rs += __shfl_xor(rs, 32, 64);
      l += rs;
      // pack P to bf16 pairs, redistribute to A-fragment layout in-register
      u32 pk0[4], pk1[4];
      #pragma unroll
      for (int n = 0; n < 4; ++n) {
        pk0[n] = cvtpk(sf[n][0], sf[n][1]);
        pk1[n] = cvtpk(sf[n][2], sf[n][3]);
      }
      bf16x8 pf[2];
      #pragma unroll
      for (int ks2 = 0; ks2 < 2; ++ks2) {
        const int na = ks2 * 2, nb = ks2 * 2 + 1;
        const u32 a0 = (u32)__shfl((int)pk0[na], srcLo, 64);
        const u32 b0 = (u32)__shfl((int)pk0[nb], srcLo, 64);
        const u32 a1 = (u32)__shfl((int)pk1[na], srcLo, 64);
        const u32 b1 = (u32)__shfl((int)pk1[nb], srcLo, 64);
        const u32 a2 = (u32)__shfl((int)pk0[na], srcHi, 64);
        const u32 b2 = (u32)__shfl((int)pk0[nb], srcHi, 64);
        const u32 a3 = (u32)__shfl((int)pk1[na], srcHi, 64);
        const u32 b3 = (u32)__shfl((int)pk1[nb], srcHi, 64);
        const u32x4 wv = {hiSel ? b0 : a0, hiSel ? b1 : a1, hiSel ? b2 : a2,
                          hiSel ? b3 : a3};
        pf[ks2] = __builtin_bit_cast(bf16x8, wv);
      }
      // O += P V
      const char* vsb0 = (const char*)&Vs[buf][0];
      __builtin_amdgcn_s_setprio(1);
      #pragma unroll
      for (int ks2 = 0; ks2 < 2; ++ks2) {
        #pragma unroll
        for (int nd = 0; nd < 8; ++nd) {
          const int row = nd * 16 + c;
          const bf16x8 vf = *(const bf16x8*)(vsb0 + row * 128 +
              ((ks2 * 64 + g * 16) ^ ((row & 7) << 4)));
          of[nd] = __builtin_amdgcn_mfma_f32_16x16x32_bf16(pf[ks2], vf, of[nd], 0, 0, 0);
        }
      }
      __builtin_amdgcn_s_setprio(0);
    }
  }

  // epilogue: ctx[b][s][h*128+dh] bf16
  const int bq = bh >> 4, hq = bh & 15;
  {
    float linv[4];
    #pragma unroll
    for (int r = 0; r < 4; ++r) linv[r] = 1.0f / __shfl(l, alS + r, 64);
    #pragma unroll
    for (int nd = 0; nd < 8; ++nd) {
      #pragma unroll
      for (int r = 0; r < 4; ++r) {
        const int row = qt * 64 + wq * 16 + g * 4 + r;
        ctx[((size_t)(bq * 2048 + row)) * 2048 + hq * 128 + nd * 16 + c] =
            f2b(of[nd][r] * linv[r]);
      }
    }
  }
#undef STAGE
}

// ---------------- host ----------------
extern "C" void kernel_launch(void* const* d_in, const int* in_sizes, int n_in,
                              void* d_out, int out_size, void* d_ws, size_t ws_size,
                              hipStream_t stream) {
  const float* hs  = (const float*)d_in[0];
  const float* Wq  = (const float*)d_in[1];
  const float* Wk  = (const float*)d_in[2];
  const float* Wv  = (const float*)d_in[3];
  const float* Wo  = (const float*)d_in[4];
  const float* Wkc = (const float*)d_in[5];
  const float* Wvc = (const float*)d_in[6];
  const float* Wke = (const float*)d_in[7];
  const float* Wve = (const float*)d_in[8];
  float* out      = (float*)d_out;
  float* out_attn = out;                  // 2*2048*2048
  float* out_kc   = out + 8388608;        // 2*16*2048*32
  float* out_vc   = out_kc + 2097152;

  char* ws = (char*)d_ws;
  u16* hsb   = (u16*)ws; ws += 16777216;   // A bf16 (later reused as khb)
  u16* BtAll = (u16*)ws; ws += 12582912;   // [3072][2048] bf16 (later part of ctxb)
  u16* kcb   = (u16*)ws; ws += 4194304;    // (later part of ctxb)
  u16* vcb   = (u16*)ws; ws += 4194304;
  u16* WoT   = (u16*)ws; ws += 8388608;
  u16* qb    = (u16*)ws; ws += 16777216;
  u16* vht   = (u16*)ws; ws += 16777216;
  u16* WkeT  = (u16*)ws; ws += 8192;
  u16* WveT  = (u16*)ws; ws += 8192;
  u16* khb   = hsb;                        // reuse after QKV GEMM
  u16* ctxb  = BtAll;                      // reuse BtAll+kcb (12.58M+4.19M = 16.78M)

  cast_k<<<8192, 256, 0, stream>>>(hs, hsb, 8388608);
  transpose_cast_k<<<dim3(64, 64), 256, 0, stream>>>(Wq, BtAll, 2048);
  transpose_cast_k<<<dim3(64, 64), 256, 0, stream>>>(Wo, WoT, 2048);
  combine_k<<<dim3(8, 16), 256, 0, stream>>>(Wk, Wkc, BtAll + (size_t)2048 * 2048, 2048);
  combine_k<<<dim3(8, 16), 256, 0, stream>>>(Wv, Wvc, BtAll + (size_t)2560 * 2048, 2048);
  wtrans_k<<<16, 256, 0, stream>>>(Wke, WkeT);
  wtrans_k<<<16, 256, 0, stream>>>(Wve, WveT);

  gemm_ring_k<192, 0><<<dim3(16, 16), 512, 0, stream>>>(
      hsb, BtAll, qb, out_kc, kcb, out_vc, vcb, nullptr);

  expand_mfma_k<0><<<dim3(32, 32), 256, 0, stream>>>(kcb, WkeT, khb);
  expand_mfma_k<1><<<dim3(32, 32), 256, 0, stream>>>(vcb, WveT, vht);

  attn_k<<<dim3(16, 32), 512, 0, stream>>>(qb, khb, vht, ctxb);

  gemm_ring_k<128, 1><<<dim3(16, 16), 512, 0, stream>>>(
      ctxb, WoT, nullptr, nullptr, nullptr, nullptr, nullptr, out_attn);
}

// Round 8
// 441.582 us; speedup vs baseline: 1.0146x; 1.0146x over previous
//
#include <hip/hip_runtime.h>

using u16 = unsigned short;
using u32 = unsigned int;

typedef __attribute__((ext_vector_type(8))) __bf16 bf16x8;
typedef __attribute__((ext_vector_type(4))) float f32x4;
typedef __attribute__((ext_vector_type(4))) u32 u32x4;

#define GLOAD16(gp, lp) __builtin_amdgcn_global_load_lds( \
    (const __attribute__((address_space(1))) void*)(gp),  \
    (__attribute__((address_space(3))) void*)(lp), 16, 0, 0)

__device__ __forceinline__ u16 f2b(float f) {
  u32 u = __builtin_bit_cast(u32, f);
  u += 0x7fffu + ((u >> 16) & 1u);
  return (u16)(u >> 16);
}
__device__ __forceinline__ float b2f(u16 h) {
  return __builtin_bit_cast(float, (u32)h << 16);
}
__device__ __forceinline__ u32 cvtpk(float lo, float hi) {
  u32 r;
  asm("v_cvt_pk_bf16_f32 %0, %1, %2" : "=v"(r) : "v"(lo), "v"(hi));
  return r;
}

// ---------------- cast hs -> bf16 ----------------
__global__ __launch_bounds__(256) void cast_k(
    const float* __restrict__ in, u16* __restrict__ o1, int n) {
  int i = (blockIdx.x * 256 + threadIdx.x) * 4;
  if (i >= n) return;
  float4 v = *(const float4*)&in[i];
  *(uint2*)&o1[i] = make_uint2((u32)f2b(v.x) | ((u32)f2b(v.y) << 16),
                               (u32)f2b(v.z) | ((u32)f2b(v.w) << 16));
}

// ---------------- transpose + cast weight: out[e][d] = in[d][e] ----------------
__global__ __launch_bounds__(256) void transpose_cast_k(
    const float* __restrict__ in, u16* __restrict__ out, int D) {
  __shared__ float t[32][33];
  const int tx = threadIdx.x & 31, ty = threadIdx.x >> 5;
  const int e0 = blockIdx.x * 32, d0 = blockIdx.y * 32;
  #pragma unroll
  for (int i = ty; i < 32; i += 8) t[i][tx] = in[(size_t)(d0 + i) * D + e0 + tx];
  __syncthreads();
  #pragma unroll
  for (int i = ty; i < 32; i += 8) out[(size_t)(e0 + i) * D + d0 + tx] = f2b(t[tx][i]);
}

// ------ combined compression weight: outT[h*32+c][d] = sum_dp Wfull[d][h*128+dp]*Wc[dp][c] ------
__global__ __launch_bounds__(256) void combine_k(
    const float* __restrict__ Wfull, const float* __restrict__ Wc,
    u16* __restrict__ outT, int D) {
  __shared__ float wl[4096];
  const int tid = threadIdx.x;
  for (int i = tid; i < 4096; i += 256) wl[i] = Wc[i];
  __syncthreads();
  const int h = blockIdx.y;
  const int d = blockIdx.x * 256 + tid;
  const float* wkr = Wfull + (size_t)d * D + h * 128;
  float acc[32] = {};
  for (int dp = 0; dp < 128; ++dp) {
    const float wv = wkr[dp];
    const float* w2 = &wl[dp * 32];
    #pragma unroll
    for (int c = 0; c < 32; ++c) acc[c] += wv * w2[c];
  }
  #pragma unroll
  for (int c = 0; c < 32; ++c)
    outT[(size_t)(h * 32 + c) * D + d] = f2b(acc[c]);
}

// ---------------- expansion weight transpose: out[d][c] = bf16(in[c][d]), 32x128 ----------------
__global__ __launch_bounds__(256) void wtrans_k(
    const float* __restrict__ in, u16* __restrict__ out) {
  const int i = blockIdx.x * 256 + threadIdx.x;  // 4096 total
  const int d = i >> 5, c = i & 31;
  out[i] = f2b(in[c * 128 + d]);
}

// ---------------- expansion via MFMA ----------------
// in: [bh][2048][32] bf16, WT: [128][32] bf16 (Wexp^T)
// TRANS=0 (K): out[bh][s][128]   TRANS=1 (V): out[bh][128][2048] (d-major)
template <int TRANS>
__global__ __launch_bounds__(256) void expand_mfma_k(
    const u16* __restrict__ in, const u16* __restrict__ WT, u16* __restrict__ out) {
  __shared__ alignas(16) u16 WL[128 * 32];
  __shared__ alignas(16) u16 ct[64 * 40];
  const int tid = threadIdx.x, lane = tid & 63, w = tid >> 6;
  const int cl = lane & 15, g = lane >> 4;
  const int bh = blockIdx.y, s0 = blockIdx.x * 64;
  for (int i = tid; i < 512; i += 256) ((uint4*)WL)[i] = ((const uint4*)WT)[i];
  {
    const int r = tid >> 2, co = (tid & 3) * 8;
    *(uint4*)&ct[r * 40 + co] =
        *(const uint4*)&in[((size_t)bh * 2048 + s0 + r) * 32 + co];
  }
  __syncthreads();
  f32x4 acc[2][4] = {};
  #pragma unroll
  for (int dti = 0; dti < 2; ++dti) {
    const bf16x8 wf = *(const bf16x8*)&WL[((w * 2 + dti) * 16 + cl) * 32 + g * 8];
    #pragma unroll
    for (int st = 0; st < 4; ++st) {
      const bf16x8 cf = *(const bf16x8*)&ct[(st * 16 + cl) * 40 + g * 8];
      if constexpr (TRANS)
        acc[dti][st] = __builtin_amdgcn_mfma_f32_16x16x32_bf16(wf, cf, acc[dti][st], 0, 0, 0);
      else
        acc[dti][st] = __builtin_amdgcn_mfma_f32_16x16x32_bf16(cf, wf, acc[dti][st], 0, 0, 0);
    }
  }
  #pragma unroll
  for (int dti = 0; dti < 2; ++dti) {
    #pragma unroll
    for (int st = 0; st < 4; ++st) {
      #pragma unroll
      for (int r = 0; r < 4; ++r) {
        if constexpr (TRANS) {
          const int d = (w * 2 + dti) * 16 + g * 4 + r;
          const int s = s0 + st * 16 + cl;
          out[((size_t)bh * 128 + d) * 2048 + s] = f2b(acc[dti][st][r]);
        } else {
          const int s = s0 + st * 16 + g * 4 + r;
          const int d = (w * 2 + dti) * 16 + cl;
          out[((size_t)bh * 2048 + s) * 128 + d] = f2b(acc[dti][st][r]);
        }
      }
    }
  }
}

// ---------------- fused QKV projection GEMM (m97 structure, 3 blocks/CU) ----------------
// C[M=4096, N=3072] = A[M,K=2048] * BtAll[N,K]^T
// cols 0..2047: Q (bf16 scatter, pre-scaled by 1/sqrt(dh)*log2(e)); 2048..2559: Kc; 2560..3071: Vc
__global__ __launch_bounds__(256) void gemm_qkv_k(
    const u16* __restrict__ A, const u16* __restrict__ Bt,
    u16* __restrict__ qb, float* __restrict__ out_kc, u16* __restrict__ kcb,
    float* __restrict__ out_vc, u16* __restrict__ vcb) {
  __shared__ alignas(16) u16 As[128 * 64];
  __shared__ alignas(16) u16 Bs[128 * 64];
  const int tid = threadIdx.x, lane = tid & 63, w = tid >> 6;
  const int l15 = lane & 15, lhi = lane >> 4;
  const int m0 = blockIdx.y * 128, n0 = blockIdx.x * 128;
  const int wr = (w >> 1) * 64, wc = (w & 1) * 64;
  const int rl = lane >> 3, cbe = (lane & 7) * 8;
  const int K = 2048;

  f32x4 acc[4][4] = {};

  for (int k0 = 0; k0 < K; k0 += 64) {
    __syncthreads();
    #pragma unroll
    for (int i = 0; i < 4; ++i) {
      const int rb = w * 32 + i * 8;
      GLOAD16(A + (size_t)(m0 + rb + rl) * K + k0 + cbe, &As[rb * 64]);
      GLOAD16(Bt + (size_t)(n0 + rb + rl) * K + k0 + cbe, &Bs[rb * 64]);
    }
    __syncthreads();
    #pragma unroll
    for (int ks = 0; ks < 2; ++ks) {
      bf16x8 af[4], bfr[4];
      #pragma unroll
      for (int m = 0; m < 4; ++m)
        af[m] = *(const bf16x8*)&As[(wr + m * 16 + l15) * 64 + ks * 32 + lhi * 8];
      #pragma unroll
      for (int n = 0; n < 4; ++n)
        bfr[n] = *(const bf16x8*)&Bs[(wc + n * 16 + l15) * 64 + ks * 32 + lhi * 8];
      #pragma unroll
      for (int m = 0; m < 4; ++m)
        #pragma unroll
        for (int n = 0; n < 4; ++n)
          acc[m][n] = __builtin_amdgcn_mfma_f32_16x16x32_bf16(af[m], bfr[n], acc[m][n], 0, 0, 0);
    }
  }

  const float qscale = 0.08838834764831845f * 1.4426950408889634f;
  #pragma unroll
  for (int m = 0; m < 4; ++m) {
    #pragma unroll
    for (int n = 0; n < 4; ++n) {
      #pragma unroll
      for (int r = 0; r < 4; ++r) {
        const int row = m0 + wr + m * 16 + lhi * 4 + r;
        const int col = n0 + wc + n * 16 + l15;
        const int b = row >> 11, s = row & 2047;
        const float v = acc[m][n][r];
        if (n0 < 2048) {
          const int h = col >> 7, dh = col & 127;
          qb[((size_t)(b * 16 + h) * 2048 + s) * 128 + dh] = f2b(v * qscale);
        } else {
          const int cc = col - 2048;
          if (cc < 512) {
            const int h = cc >> 5, c = cc & 31;
            const size_t idx = ((size_t)(b * 16 + h) * 2048 + s) * 32 + c;
            out_kc[idx] = v;
            kcb[idx] = f2b(v);
          } else {
            const int cc2 = cc - 512;
            const int h = cc2 >> 5, c = cc2 & 31;
            const size_t idx = ((size_t)(b * 16 + h) * 2048 + s) * 32 + c;
            out_vc[idx] = v;
            vcb[idx] = f2b(v);
          }
        }
      }
    }
  }
}

// ---------------- O-projection GEMM: f32 out [M,N] (m97 structure) ----------------
__global__ __launch_bounds__(256) void gemm_o_k(
    const u16* __restrict__ A, const u16* __restrict__ Bt,
    int M, int N, int K, float* __restrict__ outF) {
  __shared__ alignas(16) u16 As[128 * 64];
  __shared__ alignas(16) u16 Bs[128 * 64];
  const int tid = threadIdx.x, lane = tid & 63, w = tid >> 6;
  const int l15 = lane & 15, lhi = lane >> 4;
  const int m0 = blockIdx.y * 128, n0 = blockIdx.x * 128;
  const int wr = (w >> 1) * 64, wc = (w & 1) * 64;
  const int rl = lane >> 3, cbe = (lane & 7) * 8;

  f32x4 acc[4][4] = {};

  for (int k0 = 0; k0 < K; k0 += 64) {
    __syncthreads();
    #pragma unroll
    for (int i = 0; i < 4; ++i) {
      const int rb = w * 32 + i * 8;
      GLOAD16(A + (size_t)(m0 + rb + rl) * K + k0 + cbe, &As[rb * 64]);
      GLOAD16(Bt + (size_t)(n0 + rb + rl) * K + k0 + cbe, &Bs[rb * 64]);
    }
    __syncthreads();
    #pragma unroll
    for (int ks = 0; ks < 2; ++ks) {
      bf16x8 af[4], bfr[4];
      #pragma unroll
      for (int m = 0; m < 4; ++m)
        af[m] = *(const bf16x8*)&As[(wr + m * 16 + l15) * 64 + ks * 32 + lhi * 8];
      #pragma unroll
      for (int n = 0; n < 4; ++n)
        bfr[n] = *(const bf16x8*)&Bs[(wc + n * 16 + l15) * 64 + ks * 32 + lhi * 8];
      #pragma unroll
      for (int m = 0; m < 4; ++m)
        #pragma unroll
        for (int n = 0; n < 4; ++n)
          acc[m][n] = __builtin_amdgcn_mfma_f32_16x16x32_bf16(af[m], bfr[n], acc[m][n], 0, 0, 0);
    }
  }

  #pragma unroll
  for (int m = 0; m < 4; ++m)
    #pragma unroll
    for (int n = 0; n < 4; ++n)
      #pragma unroll
      for (int r = 0; r < 4; ++r)
        outF[(size_t)(m0 + wr + m * 16 + lhi * 4 + r) * N + n0 + wc + n * 16 + l15] =
            acc[m][n][r];
}

// ---------------- causal flash attention v5 (spill-free regalloc) ----------------
// 8 waves: waves 0-3 own q-tile A=i, waves 4-7 own q-tile B=31-i, processing the
// SAME staged K/V tile concurrently. grid (16, B*H).
// waves_per_eu(4,4): cap VGPR at 128 AND forbid the 72-VGPR 3-block spill target.
__global__ __attribute__((amdgpu_flat_work_group_size(512, 512)))
__attribute__((amdgpu_waves_per_eu(4, 4))) void attn_k(
    const u16* __restrict__ q, const u16* __restrict__ kh,
    const u16* __restrict__ vt, u16* __restrict__ ctx) {
  __shared__ alignas(16) u16 Ks[2][64 * 128];   // [k][d], XOR-swizzled 16B chunks
  __shared__ alignas(16) u16 Vs[2][128 * 64];   // [d][k], XOR-swizzled 16B chunks
  const int tid = threadIdx.x, lane = tid & 63, w = tid >> 6;
  const int grp = w >> 2, wq = w & 3;
  const int c = lane & 15, g = lane >> 4;
  const int iA = blockIdx.x, iB = 31 - iA, bh = blockIdx.y;
  const int qt = grp ? iB : iA;
  const size_t base = (size_t)bh * (2048 * 128);

  // Q fragments (B-operand layout): lane holds Q[q=c][d = ks*32+g*8 ..+7]
  bf16x8 qf[4];
  {
    const int qrow = qt * 64 + wq * 16 + c;
    #pragma unroll
    for (int ks = 0; ks < 4; ++ks)
      qf[ks] = *(const bf16x8*)&q[base + (size_t)qrow * 128 + ks * 32 + g * 8];
  }

  f32x4 of[8] = {};
  float m = -__builtin_inff(), l = 0.f;
  const int srcLo = lane ^ (((4 - g) & 3) << 4);
  const int srcHi = lane ^ (((g + 1) & 3) << 4);
  const int alS = (lane & 48) + ((lane & 48) >> 2);
  const bool hiSel = (g >> 1) != 0;

#define STAGE(J, BUF)                                                          \
  {                                                                            \
    _Pragma("unroll")                                                          \
    for (int i2 = 0; i2 < 2; ++i2) {                                           \
      const int rowgrp = w * 8 + i2 * 4;                                       \
      const int rloc = rowgrp + (lane >> 4);                                   \
      const int srce = ((c * 16) ^ ((rloc & 7) << 4)) >> 1;                    \
      GLOAD16(kh + base + (size_t)((J) * 64 + rloc) * 128 + srce,              \
              &Ks[BUF][rowgrp * 128]);                                         \
    }                                                                          \
    _Pragma("unroll")                                                          \
    for (int i2 = 0; i2 < 2; ++i2) {                                           \
      const int d0 = (w * 2 + i2) * 8;                                         \
      const int dd = d0 + (lane >> 3);                                         \
      const int cc = lane & 7;                                                 \
      GLOAD16(vt + base + (size_t)dd * 2048 + (J) * 64 + ((cc ^ (dd & 7)) * 8),\
              &Vs[BUF][d0 * 64]);                                              \
    }                                                                          \
  }

  STAGE(0, 0);
  for (int j = 0; j <= iB; ++j) {
    const int buf = j & 1;
    __syncthreads();                       // stage(j) complete (vmcnt drained)
    if (j < iB) STAGE(j + 1, buf ^ 1);     // prefetch next tile under compute
    if (j <= qt) {
      // S^T = K Q^T : sf[n][r] = S[q=c][k = n*16 + g*4 + r]
      f32x4 sf[4] = {};
      const char* ksb0 = (const char*)&Ks[buf][0];
      __builtin_amdgcn_s_setprio(1);
      #pragma unroll
      for (int n = 0; n < 4; ++n) {
        const int row = n * 16 + c;
        const char* kb = ksb0 + row * 256;
        #pragma unroll
        for (int ks = 0; ks < 4; ++ks) {
          const bf16x8 kf =
              *(const bf16x8*)(kb + ((ks * 64 + g * 16) ^ ((row & 7) << 4)));
          sf[n] = __builtin_amdgcn_mfma_f32_16x16x32_bf16(kf, qf[ks], sf[n], 0, 0, 0);
        }
      }
      __builtin_amdgcn_s_setprio(0);
      if (j == qt) {  // diagonal causal mask
        const int qloc = wq * 16 + c;
        #pragma unroll
        for (int n = 0; n < 4; ++n)
          #pragma unroll
          for (int r = 0; r < 4; ++r)
            if (n * 16 + g * 4 + r > qloc) sf[n][r] = -__builtin_inff();
      }
      // row max for q=c (in-lane 16 + cross-g)
      float smax = sf[0][0];
      #pragma unroll
      for (int n = 0; n < 4; ++n)
        #pragma unroll
        for (int r = 0; r < 4; ++r) smax = fmaxf(smax, sf[n][r]);
      smax = fmaxf(smax, __shfl_xor(smax, 16, 64));
      smax = fmaxf(smax, __shfl_xor(smax, 32, 64));
      if (__any(smax - m > 12.0f)) {  // defer-max (T13)
        const float mn = fmaxf(m, smax);
        const float al = exp2f(m - mn);
        m = mn;
        l *= al;
        float alr[4];
        #pragma unroll
        for (int r = 0; r < 4; ++r) alr[r] = __shfl(al, alS + r, 64);
        #pragma unroll
        for (int nd = 0; nd < 8; ++nd)
          #pragma unroll
          for (int r = 0; r < 4; ++r) of[nd][r] *= alr[r];
      }
      float rs = 0.f;
      #pragma unroll
      for (int n = 0; n < 4; ++n)
        #pragma unroll
        for (int r = 0; r < 4; ++r) {
          const float p = exp2f(sf[n][r] - m);
          sf[n][r] = p;
          rs += p;
        }
      rs += __shfl_xor(rs, 16, 64);
      rs += __shfl_xor(rs, 32, 64);
      l += rs;
      // pack P to bf16 pairs, redistribute to A-fragment layout in-register
      u32 pk0[4], pk1[4];
      #pragma unroll
      for (int n = 0; n < 4; ++n) {
        pk0[n] = cvtpk(sf[n][0], sf[n][1]);
        pk1[n] = cvtpk(sf[n][2], sf[n][3]);
      }
      bf16x8 pf[2];
      #pragma unroll
      for (int ks2 = 0; ks2 < 2; ++ks2) {
        const int na = ks2 * 2, nb = ks2 * 2 + 1;
        const u32 a0 = (u32)__shfl((int)pk0[na], srcLo, 64);
        const u32 b0 = (u32)__shfl((int)pk0[nb], srcLo, 64);
        const u32 a1 = (u32)__shfl((int)pk1[na], srcLo, 64);
        const u32 b1 = (u32)__shfl((int)pk1[nb], srcLo, 64);
        const u32 a2 = (u32)__shfl((int)pk0[na], srcHi, 64);
        const u32 b2 = (u32)__shfl((int)pk0[nb], srcHi, 64);
        const u32 a3 = (u32)__shfl((int)pk1[na], srcHi, 64);
        const u32 b3 = (u32)__shfl((int)pk1[nb], srcHi, 64);
        const u32x4 wv = {hiSel ? b0 : a0, hiSel ? b1 : a1, hiSel ? b2 : a2,
                          hiSel ? b3 : a3};
        pf[ks2] = __builtin_bit_cast(bf16x8, wv);
      }
      // O += P V
      const char* vsb0 = (const char*)&Vs[buf][0];
      __builtin_amdgcn_s_setprio(1);
      #pragma unroll
      for (int ks2 = 0; ks2 < 2; ++ks2) {
        #pragma unroll
        for (int nd = 0; nd < 8; ++nd) {
          const int row = nd * 16 + c;
          const bf16x8 vf = *(const bf16x8*)(vsb0 + row * 128 +
              ((ks2 * 64 + g * 16) ^ ((row & 7) << 4)));
          of[nd] = __builtin_amdgcn_mfma_f32_16x16x32_bf16(pf[ks2], vf, of[nd], 0, 0, 0);
        }
      }
      __builtin_amdgcn_s_setprio(0);
    }
  }

  // epilogue: ctx[b][s][h*128+dh] bf16
  const int bq = bh >> 4, hq = bh & 15;
  {
    float linv[4];
    #pragma unroll
    for (int r = 0; r < 4; ++r) linv[r] = 1.0f / __shfl(l, alS + r, 64);
    #pragma unroll
    for (int nd = 0; nd < 8; ++nd) {
      #pragma unroll
      for (int r = 0; r < 4; ++r) {
        const int row = qt * 64 + wq * 16 + g * 4 + r;
        ctx[((size_t)(bq * 2048 + row)) * 2048 + hq * 128 + nd * 16 + c] =
            f2b(of[nd][r] * linv[r]);
      }
    }
  }
#undef STAGE
}

// ---------------- host ----------------
extern "C" void kernel_launch(void* const* d_in, const int* in_sizes, int n_in,
                              void* d_out, int out_size, void* d_ws, size_t ws_size,
                              hipStream_t stream) {
  const float* hs  = (const float*)d_in[0];
  const float* Wq  = (const float*)d_in[1];
  const float* Wk  = (const float*)d_in[2];
  const float* Wv  = (const float*)d_in[3];
  const float* Wo  = (const float*)d_in[4];
  const float* Wkc = (const float*)d_in[5];
  const float* Wvc = (const float*)d_in[6];
  const float* Wke = (const float*)d_in[7];
  const float* Wve = (const float*)d_in[8];
  float* out      = (float*)d_out;
  float* out_attn = out;                  // 2*2048*2048
  float* out_kc   = out + 8388608;        // 2*16*2048*32
  float* out_vc   = out_kc + 2097152;

  char* ws = (char*)d_ws;
  u16* hsb   = (u16*)ws; ws += 16777216;   // A bf16 (later reused as khb)
  u16* BtAll = (u16*)ws; ws += 12582912;   // [3072][2048] bf16 (later part of ctxb)
  u16* kcb   = (u16*)ws; ws += 4194304;    // (later part of ctxb)
  u16* vcb   = (u16*)ws; ws += 4194304;
  u16* WoT   = (u16*)ws; ws += 8388608;
  u16* qb    = (u16*)ws; ws += 16777216;
  u16* vht   = (u16*)ws; ws += 16777216;
  u16* WkeT  = (u16*)ws; ws += 8192;
  u16* WveT  = (u16*)ws; ws += 8192;
  u16* khb   = hsb;                        // reuse after QKV GEMM
  u16* ctxb  = BtAll;                      // reuse BtAll+kcb (12.58M+4.19M = 16.78M)

  cast_k<<<8192, 256, 0, stream>>>(hs, hsb, 8388608);
  transpose_cast_k<<<dim3(64, 64), 256, 0, stream>>>(Wq, BtAll, 2048);
  transpose_cast_k<<<dim3(64, 64), 256, 0, stream>>>(Wo, WoT, 2048);
  combine_k<<<dim3(8, 16), 256, 0, stream>>>(Wk, Wkc, BtAll + (size_t)2048 * 2048, 2048);
  combine_k<<<dim3(8, 16), 256, 0, stream>>>(Wv, Wvc, BtAll + (size_t)2560 * 2048, 2048);
  wtrans_k<<<16, 256, 0, stream>>>(Wke, WkeT);
  wtrans_k<<<16, 256, 0, stream>>>(Wve, WveT);

  gemm_qkv_k<<<dim3(24, 32), 256, 0, stream>>>(hsb, BtAll, qb, out_kc, kcb, out_vc, vcb);

  expand_mfma_k<0><<<dim3(32, 32), 256, 0, stream>>>(kcb, WkeT, khb);
  expand_mfma_k<1><<<dim3(32, 32), 256, 0, stream>>>(vcb, WveT, vht);

  attn_k<<<dim3(16, 32), 512, 0, stream>>>(qb, khb, vht, ctxb);

  gemm_o_k<<<dim3(16, 32), 256, 0, stream>>>(ctxb, WoT, 4096, 2048, 2048, out_attn);
}